// Round 1
// 994.991 us; speedup vs baseline: 1.2582x; 1.2582x over previous
//
#include <hip/hip_runtime.h>
#include <cstdint>
#include <cstddef>

// Problem constants (fixed by the reference)
#define IN_F  4096
#define OUT_F 4096
#define MTOT  16384   // 4 * 4096 rows of x
#define RANK  16

typedef unsigned short u16;
typedef __attribute__((ext_vector_type(8))) short short8;  // 8 x bf16 (4 VGPRs)
typedef __attribute__((ext_vector_type(4))) float f32x4;

// ---- round-to-nearest-even f32 -> bf16 (no NaN inputs in this problem) ----
__device__ __forceinline__ u16 f2bf(float f) {
  union { float f; uint32_t u; } v; v.f = f;
  uint32_t u = v.u;
  return (u16)((u + 0x7fffu + ((u >> 16) & 1u)) >> 16);
}

// ---- async global->LDS, 16 bytes per lane (dest must be lane-linear per wave) ----
__device__ __forceinline__ void async_copy16(const void* g, void* l) {
  __builtin_amdgcn_global_load_lds(
      (const __attribute__((address_space(1))) unsigned int*)g,
      (__attribute__((address_space(3))) unsigned int*)l,
      16, 0, 0);
}

// =====================  kernel 1: x f32 -> bf16  =====================
__global__ __launch_bounds__(256) void cvt_x_kernel(const float* __restrict__ x,
                                                    u16* __restrict__ xb) {
  int i = blockIdx.x * 256 + threadIdx.x;
  const float4* xp = (const float4*)x;
  float4 a = xp[2 * i];
  float4 c = xp[2 * i + 1];
  union { u16 s[8]; uint4 v; } o;
  o.s[0] = f2bf(a.x); o.s[1] = f2bf(a.y); o.s[2] = f2bf(a.z); o.s[3] = f2bf(a.w);
  o.s[4] = f2bf(c.x); o.s[5] = f2bf(c.y); o.s[6] = f2bf(c.z); o.s[7] = f2bf(c.w);
  ((uint4*)xb)[i] = o.v;
}

// =====================  kernel 2: W_eff = W + B@A -> bf16  =====================
__global__ __launch_bounds__(256) void build_weff_kernel(const float* __restrict__ W,
                                                         const float* __restrict__ A,
                                                         const float* __restrict__ Bm,
                                                         u16* __restrict__ wb) {
  int idx = blockIdx.x * 256 + threadIdx.x;
  int o  = idx >> 9;            // IN_F/8 = 512 threads per row
  int i0 = (idx & 511) << 3;
  const float4* wp = (const float4*)(W + (size_t)o * IN_F + i0);
  float4 a0 = wp[0], a1 = wp[1];
  float acc[8] = {a0.x, a0.y, a0.z, a0.w, a1.x, a1.y, a1.z, a1.w};
#pragma unroll
  for (int r = 0; r < RANK; ++r) {
    float bo = Bm[(size_t)o * RANK + r];
    const float4* ap = (const float4*)(A + (size_t)r * IN_F + i0);
    float4 b0 = ap[0], b1 = ap[1];
    acc[0] += bo * b0.x; acc[1] += bo * b0.y; acc[2] += bo * b0.z; acc[3] += bo * b0.w;
    acc[4] += bo * b1.x; acc[5] += bo * b1.y; acc[6] += bo * b1.z; acc[7] += bo * b1.w;
  }
  union { u16 s[8]; uint4 v; } ov;
#pragma unroll
  for (int j = 0; j < 8; ++j) ov.s[j] = f2bf(acc[j]);
  ((uint4*)wb)[idx] = ov.v;
}

// =====================  kernel 3: 256x256 8-phase bf16 GEMM  =====================
// m201-style schedule in plain HIP:
//   - 512 threads = 8 waves (2 M x 4 N), per-wave 128x64 output, acc[8][4] f32x4
//   - LDS 128 KB: double-buffered 256x64 A-tile + 256x64 B-tile, row-XOR chunk
//     swizzle (conflict-free ds_read_b128; global_load_lds dest stays lane-linear,
//     swizzle applied on the per-lane GLOBAL address)
//   - 8 phases / iter (2 K-tiles); per phase: {ds_read subtile | 2 global_load_lds
//     prefetch} -> s_barrier -> lgkmcnt(0) -> setprio(1) 16xMFMA setprio(0) -> s_barrier
//   - counted s_waitcnt vmcnt(4) ONLY at the two tile-boundary phases (never 0 in
//     the main loop); A-frags of quadrants 2+3 both read in phase 2 => buffer
//     released a phase early => next tile's staging gets a 4-phase window.
#define BM 256
#define BN 256
#define BK 64

#define FRAG(LS, ROW, KS) \
  (*(const short8*)&(LS)[(size_t)(ROW) * BK + (size_t)((((KS) ^ ((ROW) & 7)) * 8))])

#define STG_A(BUF, KK, J) do { \
  const int r_ = (J) * 64 + rtid; \
  const int gc_ = slot ^ (r_ & 7); \
  async_copy16(xb + (size_t)(bm + r_) * IN_F + (KK) + gc_ * 8, \
               &lsA[BUF][r_ * BK + slot * 8]); \
} while (0)

#define STG_B(BUF, KK, J) do { \
  const int r_ = (J) * 64 + rtid; \
  const int gc_ = slot ^ (r_ & 7); \
  async_copy16(wb + (size_t)(bn + r_) * IN_F + (KK) + gc_ * 8, \
               &lsB[BUF][r_ * BK + slot * 8]); \
} while (0)

#define MFMA_PAIR(TM, AP) \
  _Pragma("unroll") \
  for (int tn_ = 0; tn_ < 4; ++tn_) { \
    _Pragma("unroll") \
    for (int ks_ = 0; ks_ < 2; ++ks_) { \
      acc[(TM)][tn_]     = __builtin_amdgcn_mfma_f32_16x16x32_bf16( \
          AP[0][ks_], bF[tn_][ks_], acc[(TM)][tn_], 0, 0, 0); \
      acc[(TM) + 1][tn_] = __builtin_amdgcn_mfma_f32_16x16x32_bf16( \
          AP[1][ks_], bF[tn_][ks_], acc[(TM) + 1][tn_], 0, 0, 0); \
    } \
  }

// One K-tile = 4 phases. S?A/S?B are the two prefetch issues of each phase.
#define TILE4(BUF, S0A, S0B, S1A, S1B, S2A, S2B, S3A, S3B) do {              \
  /* ---- phase q0 (tile boundary) ---- */                                   \
  S0A; S0B;                                                                  \
  asm volatile("s_waitcnt vmcnt(4)" ::: "memory");                           \
  __builtin_amdgcn_s_barrier();                                              \
  __builtin_amdgcn_sched_barrier(0);                                         \
  short8 bF[4][2], aP0[2][2], aP1[2][2], aP2[2][2], aP3[2][2];               \
  _Pragma("unroll")                                                          \
  for (int tn_ = 0; tn_ < 4; ++tn_) {                                        \
    _Pragma("unroll")                                                        \
    for (int ks_ = 0; ks_ < 2; ++ks_)                                        \
      bF[tn_][ks_] = FRAG(lsB[BUF], bRow + tn_ * 16, ks_ * 4 + fq);          \
  }                                                                          \
  _Pragma("unroll")                                                          \
  for (int i_ = 0; i_ < 2; ++i_) {                                           \
    _Pragma("unroll")                                                        \
    for (int ks_ = 0; ks_ < 2; ++ks_)                                        \
      aP0[i_][ks_] = FRAG(lsA[BUF], aRow + i_ * 16, ks_ * 4 + fq);           \
  }                                                                          \
  asm volatile("s_waitcnt lgkmcnt(0)" ::: "memory");                         \
  __builtin_amdgcn_sched_barrier(0);                                         \
  __builtin_amdgcn_s_setprio(1);                                             \
  MFMA_PAIR(0, aP0);                                                         \
  __builtin_amdgcn_s_setprio(0);                                             \
  __builtin_amdgcn_s_barrier();                                              \
  /* ---- phase q1 ---- */                                                   \
  _Pragma("unroll")                                                          \
  for (int i_ = 0; i_ < 2; ++i_) {                                           \
    _Pragma("unroll")                                                        \
    for (int ks_ = 0; ks_ < 2; ++ks_)                                        \
      aP1[i_][ks_] = FRAG(lsA[BUF], aRow + (2 + i_) * 16, ks_ * 4 + fq);     \
  }                                                                          \
  S1A; S1B;                                                                  \
  __builtin_amdgcn_s_barrier();                                              \
  asm volatile("s_waitcnt lgkmcnt(0)" ::: "memory");                         \
  __builtin_amdgcn_sched_barrier(0);                                         \
  __builtin_amdgcn_s_setprio(1);                                             \
  MFMA_PAIR(2, aP1);                                                         \
  __builtin_amdgcn_s_setprio(0);                                             \
  __builtin_amdgcn_s_barrier();                                              \
  /* ---- phase q2 (reads q2 AND q3 frags: early buffer release) ---- */     \
  _Pragma("unroll")                                                          \
  for (int i_ = 0; i_ < 2; ++i_) {                                           \
    _Pragma("unroll")                                                        \
    for (int ks_ = 0; ks_ < 2; ++ks_) {                                      \
      aP2[i_][ks_] = FRAG(lsA[BUF], aRow + (4 + i_) * 16, ks_ * 4 + fq);     \
      aP3[i_][ks_] = FRAG(lsA[BUF], aRow + (6 + i_) * 16, ks_ * 4 + fq);     \
    }                                                                        \
  }                                                                          \
  S2A; S2B;                                                                  \
  __builtin_amdgcn_s_barrier();                                              \
  asm volatile("s_waitcnt lgkmcnt(0)" ::: "memory");                         \
  __builtin_amdgcn_sched_barrier(0);                                         \
  __builtin_amdgcn_s_setprio(1);                                             \
  MFMA_PAIR(4, aP2);                                                         \
  __builtin_amdgcn_s_setprio(0);                                             \
  __builtin_amdgcn_s_barrier();                                              \
  /* ---- phase q3 (no ds_read; frags already in regs) ---- */               \
  S3A; S3B;                                                                  \
  __builtin_amdgcn_s_barrier();                                              \
  __builtin_amdgcn_sched_barrier(0);                                         \
  __builtin_amdgcn_s_setprio(1);                                             \
  MFMA_PAIR(6, aP3);                                                         \
  __builtin_amdgcn_s_setprio(0);                                             \
  __builtin_amdgcn_s_barrier();                                              \
} while (0)

__global__ __launch_bounds__(512, 2) void gemm_kernel(const u16* __restrict__ xb,
                                                      const u16* __restrict__ wb,
                                                      const float* __restrict__ bias,
                                                      float* __restrict__ out) {
  __shared__ u16 lsA[2][BM * BK];   // 2 x 32 KB
  __shared__ u16 lsB[2][BN * BK];   // 2 x 32 KB  -> 128 KB total

  const int t = threadIdx.x;

  // XCD-aware bijective swizzle: nwg = 1024 = 8 * 128
  const int bid = blockIdx.x;
  const int swz = (bid & 7) * 128 + (bid >> 3);
  const int bm = (swz >> 4) * BM;   // 64 M-tiles
  const int bn = (swz & 15) * BN;   // 16 N-tiles

  const int lane = t & 63;
  const int wr = (t >> 8) & 1;      // wave row (0..1), 128 rows each
  const int wc = (t >> 6) & 3;      // wave col (0..3), 64 cols each
  const int fr = lane & 15;
  const int fq = lane >> 4;
  const int aRow = wr * 128 + fr;
  const int bRow = wc * 64 + fr;

  // staging decomposition: 512 thr x 16 B = 64 rows (128 B each) per issue
  const int rtid = t >> 3;          // 0..63
  const int slot = t & 7;           // 16 B chunk slot within row

  f32x4 acc[8][4];
#pragma unroll
  for (int i = 0; i < 8; ++i)
#pragma unroll
    for (int j = 0; j < 4; ++j) acc[i][j] = (f32x4)0.0f;

  // -------- prologue: tile0 (k=0) fully into buf0, tile1 A-half into buf1 ----
  STG_A(0, 0, 0); STG_A(0, 0, 1); STG_A(0, 0, 2); STG_A(0, 0, 3);
  STG_B(0, 0, 0); STG_B(0, 0, 1); STG_B(0, 0, 2); STG_B(0, 0, 3);
  STG_A(1, BK, 0); STG_A(1, BK, 1);

  // -------- main loop: 2 K-tiles (buf0 then buf1) per iteration --------------
  for (int k0 = 0; k0 < IN_F; k0 += 2 * BK) {
    const int kT1 = k0 + BK;
    int kN0 = k0 + 2 * BK; if (kN0 >= IN_F) kN0 = 0;   // wrapped junk stage on
    int kN1 = k0 + 3 * BK; if (kN1 >= IN_F) kN1 = 0;   // last iters (never read)
    TILE4(0,
          STG_A(1, kT1, 2), STG_A(1, kT1, 3),
          STG_B(1, kT1, 0), STG_B(1, kT1, 1),
          STG_B(1, kT1, 2), STG_B(1, kT1, 3),
          STG_A(0, kN0, 0), STG_A(0, kN0, 1));
    TILE4(1,
          STG_A(0, kN0, 2), STG_A(0, kN0, 3),
          STG_B(0, kN0, 0), STG_B(0, kN0, 1),
          STG_B(0, kN0, 2), STG_B(0, kN0, 3),
          STG_A(1, kN1, 0), STG_A(1, kN1, 1));
  }

  // -------- epilogue: C/D layout col = lane&15, row = (lane>>4)*4 + reg ------
#pragma unroll
  for (int tn = 0; tn < 4; ++tn) {
    int n = bn + wc * 64 + tn * 16 + fr;
    float bv = bias[n];
#pragma unroll
    for (int tm = 0; tm < 8; ++tm) {
      int m0 = bm + wr * 128 + tm * 16 + fq * 4;
      f32x4 v = acc[tm][tn];
#pragma unroll
      for (int r = 0; r < 4; ++r)
        out[(size_t)(m0 + r) * OUT_F + n] = v[r] + bv;
    }
  }
}

// =====================  launch  =====================
extern "C" void kernel_launch(void* const* d_in, const int* in_sizes, int n_in,
                              void* d_out, int out_size, void* d_ws, size_t ws_size,
                              hipStream_t stream) {
  const float* x  = (const float*)d_in[0];   // [4,4096,4096]
  const float* W  = (const float*)d_in[1];   // [4096,4096]
  const float* b  = (const float*)d_in[2];   // [4096]
  const float* A  = (const float*)d_in[3];   // [16,4096]
  const float* Bm = (const float*)d_in[4];   // [4096,16]
  float* out = (float*)d_out;

  // workspace layout: xb (bf16, 128 MB) | wb (bf16, 32 MB)
  u16* xb = (u16*)d_ws;
  u16* wb = (u16*)((char*)d_ws + (size_t)MTOT * IN_F * sizeof(u16));

  cvt_x_kernel<<<(MTOT * IN_F) / 8 / 256, 256, 0, stream>>>(x, xb);
  build_weff_kernel<<<(OUT_F * IN_F) / 8 / 256, 256, 0, stream>>>(W, A, Bm, wb);
  gemm_kernel<<<dim3((MTOT / BM) * (OUT_F / BN)), dim3(512), 0, stream>>>(xb, wb, b, out);
}